// Round 1
// baseline (236.582 us; speedup 1.0000x reference)
//
#include <hip/hip_runtime.h>

// LIF neuron forward: T=8 timesteps, x shape [T*B, C, H, W] = [256,128,32,32] f32.
// Recurrence per spatial element (independent across B,C,H,W):
//   mem = beta*mem + (1-beta)*x_t ; spike = (mem >= 0.3*Vth)*Vth ;
//   mem -= spike ; out_t = spike/0.05
// Memory-bound: 134 MB in + 134 MB out => ~43 us roofline at 6.3 TB/s.
//
// Bit-exactness notes (decisions flip 0<->20, threshold is 0.4 so ZERO flips
// allowed vs the numpy reference):
//  - beta = f32(exp(f32(-0.05))). f32(-0.05) = -13421773/2^28. Correctly
//    rounded result = 15958982 * 2^-24 = 0x1.E7078Cp-1 (~0.95122945308685303).
//    True value is ~0.009 ulp above the rounding tie -- if the harness ref's
//    exp gives the 1-ulp-down value, fallback constant is 0x1.E7078Ap-1f.
//  - mem update uses __fmul_rn/__fadd_rn to forbid FMA contraction (numpy
//    evaluates beta*mem and (1-beta)*xt as separate rn-multiplies + rn-add).
//  - (1.0f - beta) is exact in f32 (both 24-bit-representable, same binade
//    borrow; result 818234*2^-24).
//  - Vth clamp relu(Vth-5e-4)+5e-4 at Vth=1.0 round-trips to exactly 1.0f
//    (verified by hand); spike/0.05f rounds to exactly 20.0f.

#define T_STEPS 8
#define S_ELEMS (32 * 128 * 32 * 32)   // per-timestep elements = 4,194,304
#define S4 (S_ELEMS / 4)               // float4 per timestep = 1,048,576
#define BLOCK 256

__global__ __launch_bounds__(BLOCK) void lif_fwd_kernel(
    const float4* __restrict__ x, const float* __restrict__ vth_ptr,
    float4* __restrict__ out) {
  const int i = blockIdx.x * BLOCK + threadIdx.x;  // float4 column index

  // Vth clamp (no-grad): relu(Vth - 5e-4) + 5e-4, all f32 rn.
  const float vth_raw = vth_ptr[0];
  const float vth = __fadd_rn(fmaxf(__fsub_rn(vth_raw, 0.0005f), 0.0f), 0.0005f);
  const float thr = __fmul_rn(0.3f, vth);      // ALPHA * Vth
  const float outval = __fdiv_rn(vth, 0.05f);  // Vth / DELTA_T (== 20.0f)

  const float beta = 0x1.E7078Cp-1f;  // f32(exp(f32(-0.05))), correctly rounded
  const float omb = __fsub_rn(1.0f, beta);  // exact

  // Independent loads first: 8 coalesced float4 streams, 16 MB apart.
  float4 xs[T_STEPS];
#pragma unroll
  for (int t = 0; t < T_STEPS; ++t) xs[t] = x[i + t * S4];

  float m0 = 0.f, m1 = 0.f, m2 = 0.f, m3 = 0.f;
#pragma unroll
  for (int t = 0; t < T_STEPS; ++t) {
    m0 = __fadd_rn(__fmul_rn(beta, m0), __fmul_rn(omb, xs[t].x));
    m1 = __fadd_rn(__fmul_rn(beta, m1), __fmul_rn(omb, xs[t].y));
    m2 = __fadd_rn(__fmul_rn(beta, m2), __fmul_rn(omb, xs[t].z));
    m3 = __fadd_rn(__fmul_rn(beta, m3), __fmul_rn(omb, xs[t].w));
    const bool s0 = (m0 >= thr), s1 = (m1 >= thr), s2 = (m2 >= thr),
               s3 = (m3 >= thr);
    float4 o;
    o.x = s0 ? outval : 0.0f;
    o.y = s1 ? outval : 0.0f;
    o.z = s2 ? outval : 0.0f;
    o.w = s3 ? outval : 0.0f;
    if (s0) m0 = __fsub_rn(m0, vth);
    if (s1) m1 = __fsub_rn(m1, vth);
    if (s2) m2 = __fsub_rn(m2, vth);
    if (s3) m3 = __fsub_rn(m3, vth);
    out[i + t * S4] = o;
  }
}

extern "C" void kernel_launch(void* const* d_in, const int* in_sizes, int n_in,
                              void* d_out, int out_size, void* d_ws,
                              size_t ws_size, hipStream_t stream) {
  const float4* x = (const float4*)d_in[0];
  const float* vth = (const float*)d_in[1];
  float4* out = (float4*)d_out;
  // S4 float4 columns / 256 threads = 4096 blocks (16 per CU).
  lif_fwd_kernel<<<S4 / BLOCK, BLOCK, 0, stream>>>(x, vth, out);
}